// Round 1
// baseline (200.401 us; speedup 1.0000x reference)
//
#include <hip/hip_runtime.h>
#include <hip/hip_bf16.h>
#include <stdint.h>

typedef float  f32x4  __attribute__((ext_vector_type(4)));
typedef __bf16 bf16x8 __attribute__((ext_vector_type(8)));
typedef __bf16 bf16x4 __attribute__((ext_vector_type(4)));

__device__ __forceinline__ f32x4 mfma16(bf16x8 a, bf16x8 b, f32x4 c) {
    return __builtin_amdgcn_mfma_f32_16x16x32_bf16(a, b, c, 0, 0, 0);
}

// ---------------- elementwise f32 -> bf16 cast (8 elems/thread) ----------------
__global__ void cast_bf16_kernel(const float* __restrict__ src,
                                 __bf16* __restrict__ dst, int n8) {
    int i = blockIdx.x * blockDim.x + threadIdx.x;
    if (i >= n8) return;
    const float4* s = reinterpret_cast<const float4*>(src) + (size_t)i * 2;
    float4 a = s[0], b = s[1];
    bf16x8 o;
    o[0] = (__bf16)a.x; o[1] = (__bf16)a.y; o[2] = (__bf16)a.z; o[3] = (__bf16)a.w;
    o[4] = (__bf16)b.x; o[5] = (__bf16)b.y; o[6] = (__bf16)b.z; o[7] = (__bf16)b.w;
    *reinterpret_cast<bf16x8*>(dst + (size_t)i * 8) = o;
}

// ---------------- avg-pool over 4 seq positions, f32 -> bf16 (4 cols/thread) ----------------
__global__ void pool_kernel(const float* __restrict__ hs,
                            __bf16* __restrict__ pooled, int n4) {
    int i = blockIdx.x * blockDim.x + threadIdx.x;
    if (i >= n4) return;
    int e   = i * 4;
    int row = e >> 10;          // b*1024 + j
    int col = e & 1023;
    int b = row >> 10, j = row & 1023;
    const float* base = hs + (((size_t)(b * 4096 + j * 4)) << 10) + col;
    float4 s0 = *(const float4*)(base);
    float4 s1 = *(const float4*)(base + 1024);
    float4 s2 = *(const float4*)(base + 2048);
    float4 s3 = *(const float4*)(base + 3072);
    bf16x4 o;
    o[0] = (__bf16)((s0.x + s1.x + s2.x + s3.x) * 0.25f);
    o[1] = (__bf16)((s0.y + s1.y + s2.y + s3.y) * 0.25f);
    o[2] = (__bf16)((s0.z + s1.z + s2.z + s3.z) * 0.25f);
    o[3] = (__bf16)((s0.w + s1.w + s2.w + s3.w) * 0.25f);
    *reinterpret_cast<bf16x4*>(pooled + e) = o;
}

// ---------------- pooled mask -> additive bias (-10000 where any nonzero) ----------------
__global__ void mask_kernel(const int* __restrict__ mask,
                            float* __restrict__ mb, int n) {
    int i = blockIdx.x * blockDim.x + threadIdx.x;
    if (i >= n) return;
    int b = i >> 10, j = i & 1023;
    const int* p = mask + b * 4096 + j * 4;
    int any = p[0] | p[1] | p[2] | p[3];
    mb[i] = any ? -10000.0f : 0.0f;
}

// ---------------- bf16 GEMM: C[m,n] = sum_k A[m,k] * W[n,k] + bias[n] ----------------
// 128x128 tile, BK=64, 4 waves (2x2 of 64x64), swizzled LDS (128B rows, byte ^= (row&7)<<4).
// TRANS==1: write output transposed per b-chunk: out[(b*1024 + n)*1024 + (m&1023)], b = m>>10.
template <int TRANS>
__global__ __launch_bounds__(256)
void gemm_bt(const __bf16* __restrict__ A, const __bf16* __restrict__ W,
             const float* __restrict__ bias, __bf16* __restrict__ C) {
    __shared__ __bf16 As[128 * 64];
    __shared__ __bf16 Bs[128 * 64];
    const int tid  = threadIdx.x;
    const int lane = tid & 63, wid = tid >> 6;
    const int lg = lane >> 4, l15 = lane & 15;
    const int wm = (wid >> 1) * 64, wn = (wid & 1) * 64;
    const int rowBase = blockIdx.x * 128, colBase = blockIdx.y * 128;

    const f32x4 zero = {0.f, 0.f, 0.f, 0.f};
    f32x4 acc[4][4];
#pragma unroll
    for (int m = 0; m < 4; ++m)
#pragma unroll
        for (int n = 0; n < 4; ++n) acc[m][n] = zero;

    const char* Ag = (const char*)(A + (size_t)rowBase * 1024);
    const char* Wg = (const char*)(W + (size_t)colBase * 1024);
    char* AsB = (char*)As;
    char* BsB = (char*)Bs;

    for (int kt = 0; kt < 16; ++kt) {
        const int k0b = kt * 128;   // 64 bf16 = 128 bytes
        __syncthreads();
#pragma unroll
        for (int p = 0; p < 4; ++p) {
            int o  = p * 4096 + tid * 16;
            int r  = o >> 7, cb = o & 127;
            int sw = r * 128 + (cb ^ ((r & 7) << 4));
            *(uint4*)(AsB + sw) = *(const uint4*)(Ag + (size_t)r * 2048 + k0b + cb);
            *(uint4*)(BsB + sw) = *(const uint4*)(Wg + (size_t)r * 2048 + k0b + cb);
        }
        __syncthreads();

        bf16x8 af[4][2], bfr[4][2];
#pragma unroll
        for (int m = 0; m < 4; ++m)
#pragma unroll
            for (int kk = 0; kk < 2; ++kk) {
                int r  = wm + m * 16 + l15;
                int cb = kk * 64 + lg * 16;
                af[m][kk] = *(const bf16x8*)(AsB + r * 128 + (cb ^ ((r & 7) << 4)));
            }
#pragma unroll
        for (int n = 0; n < 4; ++n)
#pragma unroll
            for (int kk = 0; kk < 2; ++kk) {
                int r  = wn + n * 16 + l15;
                int cb = kk * 64 + lg * 16;
                bfr[n][kk] = *(const bf16x8*)(BsB + r * 128 + (cb ^ ((r & 7) << 4)));
            }
#pragma unroll
        for (int m = 0; m < 4; ++m)
#pragma unroll
            for (int n = 0; n < 4; ++n) {
                acc[m][n] = mfma16(af[m][0], bfr[n][0], acc[m][n]);
                acc[m][n] = mfma16(af[m][1], bfr[n][1], acc[m][n]);
            }
    }

    // epilogue. C/D layout: col = lane&15, row = (lane>>4)*4 + reg  [HW-verified]
#pragma unroll
    for (int m = 0; m < 4; ++m)
#pragma unroll
        for (int n = 0; n < 4; ++n) {
            int col  = colBase + wn + n * 16 + l15;
            float bv = bias[col];
            int row0 = rowBase + wm + m * 16 + lg * 4;
            if (TRANS) {
                int b    = row0 >> 10;
                int key0 = row0 & 1023;
                bf16x4 o;
#pragma unroll
                for (int reg = 0; reg < 4; ++reg) o[reg] = (__bf16)(acc[m][n][reg] + bv);
                *reinterpret_cast<bf16x4*>(C + (((size_t)(b * 1024 + col)) << 10) + key0) = o;
            } else {
#pragma unroll
                for (int reg = 0; reg < 4; ++reg)
                    C[(size_t)(row0 + reg) * 1024 + col] = (__bf16)(acc[m][n][reg] + bv);
            }
        }
}

// ---------------- flash attention ----------------
// Q: [b*4096 + q][1024] bf16 (head h at cols h*64..), K: [b*1024 + key][1024] bf16,
// Vt: [(b*1024 + h*64 + d)][1024 keys] bf16, mb: [b*1024 + key] float bias.
// Block = 256 thr (4 waves), 64 q rows per block (16/wave), key tiles of 64.
__global__ __launch_bounds__(256)
void attn_kernel(const __bf16* __restrict__ Q, const __bf16* __restrict__ K,
                 const __bf16* __restrict__ Vt, const float* __restrict__ mb,
                 float* __restrict__ out) {
    __shared__ __bf16 Ks[64 * 64];
    __shared__ __bf16 Vs[64 * 64];
    __shared__ __bf16 Ps[64 * 64];
    const int tid  = threadIdx.x;
    const int lane = tid & 63, wid = tid >> 6;
    const int lg = lane >> 4, l15 = lane & 15;
    const int bh = blockIdx.y, b = bh >> 4, h = bh & 15;
    const int qbase = blockIdx.x * 64;

    // Q fragments held in registers for the whole kernel (A-layout: row = lane&15, k = lg*8+j)
    const __bf16* qrow = Q + (((size_t)(b * 4096 + qbase + wid * 16 + l15)) << 10) + h * 64;
    bf16x8 aq[2];
    aq[0] = *(const bf16x8*)(qrow + lg * 8);
    aq[1] = *(const bf16x8*)(qrow + 32 + lg * 8);

    const f32x4 zero = {0.f, 0.f, 0.f, 0.f};
    f32x4 acc[4];
#pragma unroll
    for (int n = 0; n < 4; ++n) acc[n] = zero;
    float mrun[4], lrun[4];
#pragma unroll
    for (int r = 0; r < 4; ++r) { mrun[r] = -3e38f; lrun[r] = 0.f; }

    const char* Kg = (const char*)(K + (((size_t)(b * 1024)) << 10) + h * 64);
    const char* Vg = (const char*)(Vt + (((size_t)(b * 1024 + h * 64)) << 10));
    const float* mbp = mb + b * 1024;
    char* KsB = (char*)Ks;
    char* VsB = (char*)Vs;
    char* PsB = (char*)Ps;

    for (int kt = 0; kt < 16; ++kt) {
        __syncthreads();   // protect Ks/Vs from overwrite while PV of prev tile in flight
#pragma unroll
        for (int p = 0; p < 2; ++p) {
            int o  = p * 4096 + tid * 16;
            int r  = o >> 7, cb = o & 127;
            int sw = r * 128 + (cb ^ ((r & 7) << 4));
            *(uint4*)(KsB + sw) = *(const uint4*)(Kg + (size_t)(kt * 64 + r) * 2048 + cb);
            *(uint4*)(VsB + sw) = *(const uint4*)(Vg + (size_t)r * 2048 + kt * 128 + cb);
        }
        __syncthreads();

        // S = (Q K^T)/8 + mask   (C layout: col=key=l15, row=q=lg*4+reg)
        f32x4 s[4];
#pragma unroll
        for (int n = 0; n < 4; ++n) {
            s[n] = zero;
#pragma unroll
            for (int kk = 0; kk < 2; ++kk) {
                int key = n * 16 + l15;
                int cb  = kk * 64 + lg * 16;
                bf16x8 bk = *(const bf16x8*)(KsB + key * 128 + (cb ^ ((key & 7) << 4)));
                s[n] = mfma16(aq[kk], bk, s[n]);
            }
        }
        float mv[4];
#pragma unroll
        for (int n = 0; n < 4; ++n) mv[n] = mbp[kt * 64 + n * 16 + l15];
#pragma unroll
        for (int n = 0; n < 4; ++n)
#pragma unroll
            for (int r = 0; r < 4; ++r) s[n][r] = s[n][r] * 0.125f + mv[n];

        // row max across the 16 lanes of the group + 4 n-tiles
        float pm[4];
#pragma unroll
        for (int r = 0; r < 4; ++r)
            pm[r] = fmaxf(fmaxf(s[0][r], s[1][r]), fmaxf(s[2][r], s[3][r]));
#pragma unroll
        for (int off = 1; off < 16; off <<= 1)
#pragma unroll
            for (int r = 0; r < 4; ++r) pm[r] = fmaxf(pm[r], __shfl_xor(pm[r], off));

        float mnew[4], scl[4];
#pragma unroll
        for (int r = 0; r < 4; ++r) {
            mnew[r] = fmaxf(mrun[r], pm[r]);
            scl[r]  = __expf(mrun[r] - mnew[r]);
            mrun[r] = mnew[r];
        }
        float rsum[4] = {0.f, 0.f, 0.f, 0.f};
#pragma unroll
        for (int n = 0; n < 4; ++n)
#pragma unroll
            for (int r = 0; r < 4; ++r) {
                float pv = __expf(s[n][r] - mnew[r]);
                s[n][r]  = pv;
                rsum[r] += pv;
            }
#pragma unroll
        for (int off = 1; off < 16; off <<= 1)
#pragma unroll
            for (int r = 0; r < 4; ++r) rsum[r] += __shfl_xor(rsum[r], off);
#pragma unroll
        for (int r = 0; r < 4; ++r) lrun[r] = lrun[r] * scl[r] + rsum[r];
#pragma unroll
        for (int n = 0; n < 4; ++n)
#pragma unroll
            for (int r = 0; r < 4; ++r) acc[n][r] *= scl[r];

        // P -> LDS (wave-private rows wid*16..+15), swizzled; same-wave write->read,
        // compiler inserts lgkmcnt (may-alias) so no barrier needed.
#pragma unroll
        for (int n = 0; n < 4; ++n)
#pragma unroll
            for (int r = 0; r < 4; ++r) {
                int q   = wid * 16 + lg * 4 + r;
                int cb2 = (n * 16 + l15) * 2;
                *(__bf16*)(PsB + q * 128 + (cb2 ^ ((q & 7) << 4))) = (__bf16)s[n][r];
            }

        // PV: ctx += P · V  (A = P[q][key], B = Vt[d][key])
#pragma unroll
        for (int kk = 0; kk < 2; ++kk) {
            int q  = wid * 16 + l15;
            int cb = kk * 64 + lg * 16;
            bf16x8 ap = *(const bf16x8*)(PsB + q * 128 + (cb ^ ((q & 7) << 4)));
#pragma unroll
            for (int n = 0; n < 4; ++n) {
                int d = n * 16 + l15;
                bf16x8 bv = *(const bf16x8*)(VsB + d * 128 + (cb ^ ((d & 7) << 4)));
                acc[n] = mfma16(ap, bv, acc[n]);
            }
        }
    }

    // epilogue: normalize and store fp32
#pragma unroll
    for (int n = 0; n < 4; ++n)
#pragma unroll
        for (int r = 0; r < 4; ++r) {
            size_t row = (size_t)(b * 4096 + qbase + wid * 16 + lg * 4 + r);
            out[(row << 10) + h * 64 + n * 16 + l15] = acc[n][r] / lrun[r];
        }
}

extern "C" void kernel_launch(void* const* d_in, const int* in_sizes, int n_in,
                              void* d_out, int out_size, void* d_ws, size_t ws_size,
                              hipStream_t stream) {
    const float* hs    = (const float*)d_in[0];
    const int*   amask = (const int*)d_in[1];
    const float* Wq    = (const float*)d_in[2];
    const float* bq    = (const float*)d_in[3];
    const float* Wk    = (const float*)d_in[4];
    const float* bk    = (const float*)d_in[5];
    const float* Wv    = (const float*)d_in[6];
    const float* bv    = (const float*)d_in[7];
    float* out = (float*)d_out;

    char* ws = (char*)d_ws;
    size_t off = 0;
    auto alloc = [&](size_t bytes) -> char* {
        char* p = ws + off;
        off += (bytes + 255) & ~(size_t)255;
        return p;
    };
    __bf16* hsb   = (__bf16*)alloc(8388608ull * 2);  // hidden bf16 [2*4096][1024]
    __bf16* qb    = (__bf16*)alloc(8388608ull * 2);  // Q bf16
    __bf16* poolb = (__bf16*)alloc(2097152ull * 2);  // pooled bf16 [2*1024][1024]
    __bf16* kb    = (__bf16*)alloc(2097152ull * 2);  // K bf16
    __bf16* vtb   = (__bf16*)alloc(2097152ull * 2);  // V^T bf16 [b,h,d][key]
    __bf16* wqb   = (__bf16*)alloc(1048576ull * 2);
    __bf16* wkb   = (__bf16*)alloc(1048576ull * 2);
    __bf16* wvb   = (__bf16*)alloc(1048576ull * 2);
    float*  mbf   = (float*)alloc(2048 * 4);

    cast_bf16_kernel<<<4096, 256, 0, stream>>>(hs, hsb, 1048576);
    cast_bf16_kernel<<<512, 256, 0, stream>>>(Wq, wqb, 131072);
    cast_bf16_kernel<<<512, 256, 0, stream>>>(Wk, wkb, 131072);
    cast_bf16_kernel<<<512, 256, 0, stream>>>(Wv, wvb, 131072);
    pool_kernel<<<2048, 256, 0, stream>>>(hs, poolb, 524288);
    mask_kernel<<<8, 256, 0, stream>>>(amask, mbf, 2048);

    gemm_bt<0><<<dim3(64, 8), 256, 0, stream>>>(hsb, wqb, bq, qb);     // Q: M=8192
    gemm_bt<0><<<dim3(16, 8), 256, 0, stream>>>(poolb, wkb, bk, kb);   // K: M=2048
    gemm_bt<1><<<dim3(16, 8), 256, 0, stream>>>(poolb, wvb, bv, vtb);  // V^T: M=2048

    attn_kernel<<<dim3(64, 32), 256, 0, stream>>>(qb, kb, vtb, mbf, out);
}

// Round 2
// 135.190 us; speedup vs baseline: 1.4824x; 1.4824x over previous
//
#include <hip/hip_runtime.h>
#include <hip/hip_bf16.h>
#include <stdint.h>

typedef float  f32x4  __attribute__((ext_vector_type(4)));
typedef __bf16 bf16x8 __attribute__((ext_vector_type(8)));
typedef __bf16 bf16x4 __attribute__((ext_vector_type(4)));

__device__ __forceinline__ f32x4 mfma16(bf16x8 a, bf16x8 b, f32x4 c) {
    return __builtin_amdgcn_mfma_f32_16x16x32_bf16(a, b, c, 0, 0, 0);
}

// async global->LDS, 16B per lane. dest = wave-uniform base + lane*16 (per-lane
// pointer ok: compiler takes first lane's base, HW adds lane*16).
__device__ __forceinline__ void gload16(const void* g, void* lds) {
    __builtin_amdgcn_global_load_lds(
        (const __attribute__((address_space(1))) uint32_t*)g,
        (__attribute__((address_space(3))) uint32_t*)lds, 16, 0, 0);
}

// ---------------- elementwise f32 -> bf16 cast with scale (8 elems/thread) ----------------
__global__ void cast_bf16_kernel(const float* __restrict__ src,
                                 __bf16* __restrict__ dst, int n8, float scale) {
    int i = blockIdx.x * blockDim.x + threadIdx.x;
    if (i >= n8) return;
    const float4* s = reinterpret_cast<const float4*>(src) + (size_t)i * 2;
    float4 a = s[0], b = s[1];
    bf16x8 o;
    o[0] = (__bf16)(a.x * scale); o[1] = (__bf16)(a.y * scale);
    o[2] = (__bf16)(a.z * scale); o[3] = (__bf16)(a.w * scale);
    o[4] = (__bf16)(b.x * scale); o[5] = (__bf16)(b.y * scale);
    o[6] = (__bf16)(b.z * scale); o[7] = (__bf16)(b.w * scale);
    *reinterpret_cast<bf16x8*>(dst + (size_t)i * 8) = o;
}

// ---------------- avg-pool over 4 seq positions, f32 -> bf16 ----------------
__global__ void pool_kernel(const float* __restrict__ hs,
                            __bf16* __restrict__ pooled, int n4) {
    int i = blockIdx.x * blockDim.x + threadIdx.x;
    if (i >= n4) return;
    int e   = i * 4;
    int row = e >> 10;
    int col = e & 1023;
    int b = row >> 10, j = row & 1023;
    const float* base = hs + (((size_t)(b * 4096 + j * 4)) << 10) + col;
    float4 s0 = *(const float4*)(base);
    float4 s1 = *(const float4*)(base + 1024);
    float4 s2 = *(const float4*)(base + 2048);
    float4 s3 = *(const float4*)(base + 3072);
    bf16x4 o;
    o[0] = (__bf16)((s0.x + s1.x + s2.x + s3.x) * 0.25f);
    o[1] = (__bf16)((s0.y + s1.y + s2.y + s3.y) * 0.25f);
    o[2] = (__bf16)((s0.z + s1.z + s2.z + s3.z) * 0.25f);
    o[3] = (__bf16)((s0.w + s1.w + s2.w + s3.w) * 0.25f);
    *reinterpret_cast<bf16x4*>(pooled + e) = o;
}

// ---------------- pooled mask -> additive bias ----------------
__global__ void mask_kernel(const int* __restrict__ mask,
                            float* __restrict__ mb, int n) {
    int i = blockIdx.x * blockDim.x + threadIdx.x;
    if (i >= n) return;
    int b = i >> 10, j = i & 1023;
    const int* p = mask + b * 4096 + j * 4;
    int any = p[0] | p[1] | p[2] | p[3];
    mb[i] = any ? -10000.0f : 0.0f;
}

// ---------------- bf16 GEMM: C[m,n] = sum_k A[m,k]*W[n,k] + bias[n]*bscale ----------------
// 128x128 tile, BK=64, 4 waves. global_load_lds staging: linear LDS dest,
// pre-swizzled global source (XOR involution), swizzled reads.
// MODE 0: plain row-major bf16 out to C0.
// MODE 2: fused KV. col<1024 -> K rows to C0 (bias0); col>=1024 -> V^T to C1 (bias1),
//         layout C1[(b*1024 + dcol)*1024 + key].
template <int MODE>
__global__ __launch_bounds__(256)
void gemm_bt(const __bf16* __restrict__ A, const __bf16* __restrict__ W,
             const float* __restrict__ bias0, const float* __restrict__ bias1,
             float bscale, __bf16* __restrict__ C0, __bf16* __restrict__ C1) {
    __shared__ __bf16 As[128 * 64];
    __shared__ __bf16 Bs[128 * 64];
    const int tid  = threadIdx.x;
    const int lane = tid & 63, wid = tid >> 6;
    const int lg = lane >> 4, l15 = lane & 15;
    const int wm = (wid >> 1) * 64, wn = (wid & 1) * 64;
    const int rowBase = blockIdx.x * 128, colBase = blockIdx.y * 128;

    const f32x4 zero = {0.f, 0.f, 0.f, 0.f};
    f32x4 acc[4][4];
#pragma unroll
    for (int m = 0; m < 4; ++m)
#pragma unroll
        for (int n = 0; n < 4; ++n) acc[m][n] = zero;

    const char* Ag = (const char*)(A + (size_t)rowBase * 1024);
    const char* Wg = (const char*)(W + (size_t)colBase * 1024);
    char* AsB = (char*)As;
    char* BsB = (char*)Bs;

    // stage geometry: 4 chunks of 16B per thread per matrix
    const char* ag[4]; const char* wg[4]; int ld[4];
#pragma unroll
    for (int p = 0; p < 4; ++p) {
        int o  = p * 4096 + tid * 16;
        int r  = o >> 7, cb = o & 127;
        int cs = cb ^ ((r & 7) << 4);
        ag[p] = Ag + (size_t)r * 2048 + cs;
        wg[p] = Wg + (size_t)r * 2048 + cs;
        ld[p] = o;
    }

    for (int kt = 0; kt < 16; ++kt) {
        const int k0b = kt * 128;
        __syncthreads();
#pragma unroll
        for (int p = 0; p < 4; ++p) {
            gload16(ag[p] + k0b, AsB + ld[p]);
            gload16(wg[p] + k0b, BsB + ld[p]);
        }
        __syncthreads();   // drains vmcnt -> LDS tiles ready

        bf16x8 af[4][2], bfr[4][2];
#pragma unroll
        for (int m = 0; m < 4; ++m)
#pragma unroll
            for (int kk = 0; kk < 2; ++kk) {
                int r  = wm + m * 16 + l15;
                int cb = kk * 64 + lg * 16;
                af[m][kk] = *(const bf16x8*)(AsB + r * 128 + (cb ^ ((r & 7) << 4)));
            }
#pragma unroll
        for (int n = 0; n < 4; ++n)
#pragma unroll
            for (int kk = 0; kk < 2; ++kk) {
                int r  = wn + n * 16 + l15;
                int cb = kk * 64 + lg * 16;
                bfr[n][kk] = *(const bf16x8*)(BsB + r * 128 + (cb ^ ((r & 7) << 4)));
            }
#pragma unroll
        for (int m = 0; m < 4; ++m)
#pragma unroll
            for (int n = 0; n < 4; ++n) {
                acc[m][n] = mfma16(af[m][0], bfr[n][0], acc[m][n]);
                acc[m][n] = mfma16(af[m][1], bfr[n][1], acc[m][n]);
            }
    }

    // epilogue. C layout: col = lane&15, row = (lane>>4)*4 + reg
#pragma unroll
    for (int m = 0; m < 4; ++m)
#pragma unroll
        for (int n = 0; n < 4; ++n) {
            int col  = colBase + wn + n * 16 + l15;
            int row0 = rowBase + wm + m * 16 + lg * 4;
            if (MODE == 2 && col >= 1024) {
                float bv = bias1[col - 1024] * bscale;
                int bb   = row0 >> 10;
                int key0 = row0 & 1023;
                bf16x4 o;
#pragma unroll
                for (int reg = 0; reg < 4; ++reg) o[reg] = (__bf16)(acc[m][n][reg] + bv);
                *reinterpret_cast<bf16x4*>(C1 + (((size_t)(bb * 1024 + (col - 1024))) << 10) + key0) = o;
            } else {
                float bv = bias0[col] * bscale;
#pragma unroll
                for (int reg = 0; reg < 4; ++reg)
                    C0[(size_t)(row0 + reg) * 1024 + col] = (__bf16)(acc[m][n][reg] + bv);
            }
        }
}

// ---------------- flash attention, fixed-max softmax, swapped QK^T ----------------
// Q pre-scaled by 1/8 (folded into Wq/bq). mask additive -10000 -> exp underflows to 0.
// Per block: 64 q rows (4 waves x 16), KV tiles of 64, double-buffered via global_load_lds.
__global__ __launch_bounds__(256)
void attn_kernel(const __bf16* __restrict__ Q, const __bf16* __restrict__ K,
                 const __bf16* __restrict__ Vt, const float* __restrict__ mb,
                 float* __restrict__ out) {
    __shared__ __bf16 Ks[2][64 * 64];
    __shared__ __bf16 Vs[2][64 * 64];
    __shared__ __bf16 Ps[64 * 64];
    const int tid  = threadIdx.x;
    const int lane = tid & 63, wid = tid >> 6;
    const int lg = lane >> 4, l15 = lane & 15;
    const int bh = blockIdx.y, b = bh >> 4, h = bh & 15;
    const int qbase = blockIdx.x * 64;

    // Q fragment (A/B layout identical for 16x16x32): row/col = l15, k = lg*8+j
    const __bf16* qrow = Q + (((size_t)(b * 4096 + qbase + wid * 16 + l15)) << 10) + h * 64;
    bf16x8 aq[2];
    aq[0] = *(const bf16x8*)(qrow + lg * 8);
    aq[1] = *(const bf16x8*)(qrow + 32 + lg * 8);

    const f32x4 zero = {0.f, 0.f, 0.f, 0.f};
    f32x4 acc[4];
#pragma unroll
    for (int n = 0; n < 4; ++n) acc[n] = zero;
    float rs = 0.f;   // per-lane partial row sum (q = wid*16 + l15)

    const char* Kg = (const char*)(K + (((size_t)(b * 1024)) << 10) + h * 64);
    const char* Vg = (const char*)(Vt + (((size_t)(b * 1024 + h * 64)) << 10));
    const float* mbp = mb + b * 1024;

    char* PsB = (char*)Ps;
    const int qrowL = wid * 16 + l15;
    const int pswz  = (qrowL & 7) << 4;
    const int prow  = qrowL * 128;

    // stage geometry: 2 chunks of 16B per thread for K, 2 for V
    const char* kg[2]; const char* vg[2]; int ld[2];
#pragma unroll
    for (int p = 0; p < 2; ++p) {
        int o  = p * 4096 + tid * 16;
        int r  = o >> 7, cb = o & 127;
        int cs = cb ^ ((r & 7) << 4);
        kg[p] = Kg + (size_t)r * 2048 + cs;   // + kt*64 rows = kt*131072 bytes
        vg[p] = Vg + (size_t)r * 2048 + cs;   // + kt*128 bytes (key axis)
        ld[p] = o;
    }

    // prologue: tile 0 -> buf 0
#pragma unroll
    for (int p = 0; p < 2; ++p) {
        gload16(kg[p], (char*)Ks[0] + ld[p]);
        gload16(vg[p], (char*)Vs[0] + ld[p]);
    }

    int cur = 0;
    for (int kt = 0; kt < 16; ++kt) {
        __syncthreads();   // buf[cur] ready (drains vmcnt+lgkm), buf[cur^1] free
        if (kt < 15) {
#pragma unroll
            for (int p = 0; p < 2; ++p) {
                gload16(kg[p] + (size_t)(kt + 1) * 131072, (char*)Ks[cur ^ 1] + ld[p]);
                gload16(vg[p] + (kt + 1) * 128,            (char*)Vs[cur ^ 1] + ld[p]);
            }
        }
        const char* KsB = (const char*)Ks[cur];
        const char* VsB = (const char*)Vs[cur];

        // S^T = K·Q^T  (C: col = q = l15, row = key = lg*4 + reg)
        f32x4 s[4];
#pragma unroll
        for (int n = 0; n < 4; ++n) {
            s[n] = zero;
#pragma unroll
            for (int kk = 0; kk < 2; ++kk) {
                int key = n * 16 + l15;
                bf16x8 bk = *(const bf16x8*)(KsB + key * 128 + ((kk * 64 + lg * 16) ^ ((key & 7) << 4)));
                s[n] = mfma16(bk, aq[kk], s[n]);
            }
        }

        // p = exp(s + mask); accumulate row sum; write P (4 consecutive keys -> b64)
#pragma unroll
        for (int n = 0; n < 4; ++n) {
            float4 mv = *(const float4*)(mbp + kt * 64 + n * 16 + lg * 4);
            float p0 = __expf(s[n][0] + mv.x);
            float p1 = __expf(s[n][1] + mv.y);
            float p2 = __expf(s[n][2] + mv.z);
            float p3 = __expf(s[n][3] + mv.w);
            rs += (p0 + p1) + (p2 + p3);
            bf16x4 o;
            o[0] = (__bf16)p0; o[1] = (__bf16)p1; o[2] = (__bf16)p2; o[3] = (__bf16)p3;
            *(bf16x4*)(PsB + prow + ((n * 32 + lg * 8) ^ pswz)) = o;
        }

        // PV: ctx += P·V  (A = P[q][key] row q=l15, B = Vt[d][key] col d=l15)
#pragma unroll
        for (int kk = 0; kk < 2; ++kk) {
            bf16x8 ap = *(const bf16x8*)(PsB + prow + ((kk * 64 + lg * 16) ^ pswz));
#pragma unroll
            for (int n = 0; n < 4; ++n) {
                int d = n * 16 + l15;
                bf16x8 bv = *(const bf16x8*)(VsB + d * 128 + ((kk * 64 + lg * 16) ^ ((d & 7) << 4)));
                acc[n] = mfma16(ap, bv, acc[n]);
            }
        }
        cur ^= 1;
    }

    // final row-sum reduce: lanes (lg varying, same l15) hold partials for q = wid*16+l15
    rs += __shfl_xor(rs, 16);
    rs += __shfl_xor(rs, 32);
    // redistribute: epilogue lane needs sums for q = wid*16 + lg*4 + r (lives at lane lg*4+r)
    float inv[4];
#pragma unroll
    for (int r = 0; r < 4; ++r) inv[r] = 1.0f / __shfl(rs, lg * 4 + r);

#pragma unroll
    for (int n = 0; n < 4; ++n)
#pragma unroll
        for (int r = 0; r < 4; ++r) {
            size_t row = (size_t)(b * 4096 + qbase + wid * 16 + lg * 4 + r);
            out[(row << 10) + h * 64 + n * 16 + l15] = acc[n][r] * inv[r];
        }
}

extern "C" void kernel_launch(void* const* d_in, const int* in_sizes, int n_in,
                              void* d_out, int out_size, void* d_ws, size_t ws_size,
                              hipStream_t stream) {
    const float* hs    = (const float*)d_in[0];
    const int*   amask = (const int*)d_in[1];
    const float* Wq    = (const float*)d_in[2];
    const float* bq    = (const float*)d_in[3];
    const float* Wk    = (const float*)d_in[4];
    const float* bk    = (const float*)d_in[5];
    const float* Wv    = (const float*)d_in[6];
    const float* bv    = (const float*)d_in[7];
    float* out = (float*)d_out;

    char* ws = (char*)d_ws;
    size_t off = 0;
    auto alloc = [&](size_t bytes) -> char* {
        char* p = ws + off;
        off += (bytes + 255) & ~(size_t)255;
        return p;
    };
    __bf16* hsb   = (__bf16*)alloc(8388608ull * 2);  // hidden bf16 [8192][1024]
    __bf16* qb    = (__bf16*)alloc(8388608ull * 2);  // Q bf16 (pre-scaled by 1/8)
    __bf16* poolb = (__bf16*)alloc(2097152ull * 2);  // pooled bf16 [2048][1024]
    __bf16* kb    = (__bf16*)alloc(2097152ull * 2);  // K bf16
    __bf16* vtb   = (__bf16*)alloc(2097152ull * 2);  // V^T bf16 [b,h,d][key]
    __bf16* wqb   = (__bf16*)alloc(1048576ull * 2);  // Wq * 0.125
    __bf16* wkvb  = (__bf16*)alloc(2097152ull * 2);  // [Wk ; Wv] rows 0..2047
    float*  mbf   = (float*)alloc(2048 * 4);

    const float qscale = 0.125f;   // 1/sqrt(DH)=1/8 folded into Q

    cast_bf16_kernel<<<4096, 256, 0, stream>>>(hs, hsb, 1048576, 1.0f);
    cast_bf16_kernel<<<512, 256, 0, stream>>>(Wq, wqb, 131072, qscale);
    cast_bf16_kernel<<<512, 256, 0, stream>>>(Wk, wkvb, 131072, 1.0f);
    cast_bf16_kernel<<<512, 256, 0, stream>>>(Wv, wkvb + 1048576, 131072, 1.0f);
    pool_kernel<<<2048, 256, 0, stream>>>(hs, poolb, 524288);
    mask_kernel<<<8, 256, 0, stream>>>(amask, mbf, 2048);

    // Q = hs @ (Wq*s)^T + bq*s
    gemm_bt<0><<<dim3(64, 8), 256, 0, stream>>>(hsb, wqb, bq, bq, qscale, qb, qb);
    // fused K + V^T from pooled
    gemm_bt<2><<<dim3(16, 16), 256, 0, stream>>>(poolb, wkvb, bk, bv, 1.0f, kb, vtb);

    attn_kernel<<<dim3(64, 32), 256, 0, stream>>>(qb, kb, vtb, mbf, out);
}

// Round 3
// 103.964 us; speedup vs baseline: 1.9276x; 1.3004x over previous
//
#include <hip/hip_runtime.h>
#include <hip/hip_bf16.h>
#include <stdint.h>

typedef float  f32x4  __attribute__((ext_vector_type(4)));
typedef __bf16 bf16x8 __attribute__((ext_vector_type(8)));
typedef __bf16 bf16x4 __attribute__((ext_vector_type(4)));

#define LOG2E 1.44269504088896340736f

__device__ __forceinline__ f32x4 mfma16(bf16x8 a, bf16x8 b, f32x4 c) {
    return __builtin_amdgcn_mfma_f32_16x16x32_bf16(a, b, c, 0, 0, 0);
}

__device__ __forceinline__ float fast_exp2(float x) {
#if __has_builtin(__builtin_amdgcn_exp2f)
    return __builtin_amdgcn_exp2f(x);
#else
    return exp2f(x);
#endif
}

// async global->LDS, 16B per lane (wave-uniform base + lane*16 dest).
__device__ __forceinline__ void gload16(const void* g, void* lds) {
    __builtin_amdgcn_global_load_lds(
        (const __attribute__((address_space(1))) uint32_t*)g,
        (__attribute__((address_space(3))) uint32_t*)lds, 16, 0, 0);
}

// ---------------- fused cast(hs)+avgpool: one read of hs ----------------
// thread i: pooled row j = i>>7 (b*1024+t), col chunk c = (i&127)*8.
// writes 4 bf16x8 rows of hsb + 1 bf16x8 of poolb.
__global__ void cast_pool_kernel(const float* __restrict__ hs,
                                 __bf16* __restrict__ hsb,
                                 __bf16* __restrict__ poolb, int n) {
    int i = blockIdx.x * blockDim.x + threadIdx.x;
    if (i >= n) return;
    int j = i >> 7;
    int c = (i & 127) * 8;
    int b = j >> 10, t = j & 1023;
    size_t rowg = (size_t)(b * 4096 + t * 4);
    const float* base = hs + (rowg << 10) + c;
    float sum[8];
#pragma unroll
    for (int e = 0; e < 8; ++e) sum[e] = 0.f;
#pragma unroll
    for (int r = 0; r < 4; ++r) {
        float4 a = *(const float4*)(base + (size_t)r * 1024);
        float4 d = *(const float4*)(base + (size_t)r * 1024 + 4);
        bf16x8 o;
        o[0] = (__bf16)a.x; o[1] = (__bf16)a.y; o[2] = (__bf16)a.z; o[3] = (__bf16)a.w;
        o[4] = (__bf16)d.x; o[5] = (__bf16)d.y; o[6] = (__bf16)d.z; o[7] = (__bf16)d.w;
        *reinterpret_cast<bf16x8*>(hsb + ((rowg + r) << 10) + c) = o;
        sum[0] += a.x; sum[1] += a.y; sum[2] += a.z; sum[3] += a.w;
        sum[4] += d.x; sum[5] += d.y; sum[6] += d.z; sum[7] += d.w;
    }
    bf16x8 p;
#pragma unroll
    for (int e = 0; e < 8; ++e) p[e] = (__bf16)(sum[e] * 0.25f);
    *reinterpret_cast<bf16x8*>(poolb + ((size_t)j << 10) + c) = p;
}

// ---------------- all three weight casts in one launch ----------------
__global__ void cast_w_kernel(const float* __restrict__ Wq, const float* __restrict__ Wk,
                              const float* __restrict__ Wv, __bf16* __restrict__ wqb,
                              __bf16* __restrict__ wkvb, float qscale, int n) {
    int i = blockIdx.x * blockDim.x + threadIdx.x;
    if (i >= n) return;
    const float* src; __bf16* dst; float sc; int j;
    if (i < 131072)      { src = Wq; dst = wqb;            sc = qscale; j = i; }
    else if (i < 262144) { src = Wk; dst = wkvb;           sc = 1.f;    j = i - 131072; }
    else                 { src = Wv; dst = wkvb + 1048576; sc = 1.f;    j = i - 262144; }
    const float4* s = reinterpret_cast<const float4*>(src) + (size_t)j * 2;
    float4 a = s[0], b = s[1];
    bf16x8 o;
    o[0] = (__bf16)(a.x * sc); o[1] = (__bf16)(a.y * sc);
    o[2] = (__bf16)(a.z * sc); o[3] = (__bf16)(a.w * sc);
    o[4] = (__bf16)(b.x * sc); o[5] = (__bf16)(b.y * sc);
    o[6] = (__bf16)(b.z * sc); o[7] = (__bf16)(b.w * sc);
    *reinterpret_cast<bf16x8*>(dst + (size_t)j * 8) = o;
}

// ---------------- pooled mask -> additive log2-domain bias ----------------
__global__ void mask_kernel(const int* __restrict__ mask,
                            float* __restrict__ mb, int n) {
    int i = blockIdx.x * blockDim.x + threadIdx.x;
    if (i >= n) return;
    int b = i >> 10, j = i & 1023;
    const int* p = mask + b * 4096 + j * 4;
    int any = p[0] | p[1] | p[2] | p[3];
    mb[i] = any ? (-10000.0f * LOG2E) : 0.0f;
}

// ---------------- fused Q + KV GEMM: C = A @ W^T + bias ----------------
// 1D grid of 768 blocks. id<512: Q path (hsb@wqb^T -> qb, bias bq*qscale).
// id>=512: KV path (poolb@wkvb^T): col<1024 -> kb; col>=1024 -> vtb transposed.
// 128x128 tile, BK=64, 4 waves, global_load_lds with pre-swizzled source.
__global__ __launch_bounds__(256)
void gemm_fused(const __bf16* __restrict__ hsb, const __bf16* __restrict__ poolb,
                const __bf16* __restrict__ wqb, const __bf16* __restrict__ wkvb,
                const float* __restrict__ bq, const float* __restrict__ bk,
                const float* __restrict__ bv, float qscale,
                __bf16* __restrict__ qb, __bf16* __restrict__ kb,
                __bf16* __restrict__ vtb) {
    __shared__ __bf16 As[128 * 64];
    __shared__ __bf16 Bs[128 * 64];
    const int tid  = threadIdx.x;
    const int lane = tid & 63, wid = tid >> 6;
    const int lg = lane >> 4, l15 = lane & 15;
    const int wm = (wid >> 1) * 64, wn = (wid & 1) * 64;

    const int id = blockIdx.x;
    const bool isQ = (id < 512);
    const int bx = isQ ? (id & 63) : ((id - 512) & 15);
    const int by = isQ ? (id >> 6) : ((id - 512) >> 4);
    const __bf16* A = isQ ? hsb : poolb;
    const __bf16* W = isQ ? wqb : wkvb;
    const int rowBase = bx * 128, colBase = by * 128;

    const f32x4 zero = {0.f, 0.f, 0.f, 0.f};
    f32x4 acc[4][4];
#pragma unroll
    for (int m = 0; m < 4; ++m)
#pragma unroll
        for (int n = 0; n < 4; ++n) acc[m][n] = zero;

    const char* Ag = (const char*)(A + (size_t)rowBase * 1024);
    const char* Wg = (const char*)(W + (size_t)colBase * 1024);
    char* AsB = (char*)As;
    char* BsB = (char*)Bs;

    const char* ag[4]; const char* wg[4]; int ld[4];
#pragma unroll
    for (int p = 0; p < 4; ++p) {
        int o  = p * 4096 + tid * 16;
        int r  = o >> 7, cb = o & 127;
        int cs = cb ^ ((r & 7) << 4);
        ag[p] = Ag + (size_t)r * 2048 + cs;
        wg[p] = Wg + (size_t)r * 2048 + cs;
        ld[p] = o;
    }

    for (int kt = 0; kt < 16; ++kt) {
        const int k0b = kt * 128;
        __syncthreads();
#pragma unroll
        for (int p = 0; p < 4; ++p) {
            gload16(ag[p] + k0b, AsB + ld[p]);
            gload16(wg[p] + k0b, BsB + ld[p]);
        }
        __syncthreads();

        bf16x8 af[4][2], bfr[4][2];
#pragma unroll
        for (int m = 0; m < 4; ++m)
#pragma unroll
            for (int kk = 0; kk < 2; ++kk) {
                int r  = wm + m * 16 + l15;
                int cb = kk * 64 + lg * 16;
                af[m][kk] = *(const bf16x8*)(AsB + r * 128 + (cb ^ ((r & 7) << 4)));
            }
#pragma unroll
        for (int n = 0; n < 4; ++n)
#pragma unroll
            for (int kk = 0; kk < 2; ++kk) {
                int r  = wn + n * 16 + l15;
                int cb = kk * 64 + lg * 16;
                bfr[n][kk] = *(const bf16x8*)(BsB + r * 128 + (cb ^ ((r & 7) << 4)));
            }
#pragma unroll
        for (int m = 0; m < 4; ++m)
#pragma unroll
            for (int n = 0; n < 4; ++n) {
                acc[m][n] = mfma16(af[m][0], bfr[n][0], acc[m][n]);
                acc[m][n] = mfma16(af[m][1], bfr[n][1], acc[m][n]);
            }
    }

    // epilogue. C layout: col = lane&15, row = (lane>>4)*4 + reg
#pragma unroll
    for (int m = 0; m < 4; ++m)
#pragma unroll
        for (int n = 0; n < 4; ++n) {
            int col  = colBase + wn + n * 16 + l15;
            int row0 = rowBase + wm + m * 16 + lg * 4;
            if (isQ) {
                float bvl = bq[col] * qscale;
#pragma unroll
                for (int reg = 0; reg < 4; ++reg)
                    qb[(size_t)(row0 + reg) * 1024 + col] = (__bf16)(acc[m][n][reg] + bvl);
            } else if (col < 1024) {
                float bvl = bk[col];
#pragma unroll
                for (int reg = 0; reg < 4; ++reg)
                    kb[(size_t)(row0 + reg) * 1024 + col] = (__bf16)(acc[m][n][reg] + bvl);
            } else {
                float bvl = bv[col - 1024];
                int bb   = row0 >> 10;
                int key0 = row0 & 1023;
                bf16x4 o;
#pragma unroll
                for (int reg = 0; reg < 4; ++reg) o[reg] = (__bf16)(acc[m][n][reg] + bvl);
                *reinterpret_cast<bf16x4*>(vtb + (((size_t)(bb * 1024 + (col - 1024))) << 10) + key0) = o;
            }
        }
}

// ---------------- flash attention: 4 waves x 64 q rows, fixed-max exp2 softmax ----------------
// Q pre-scaled by 0.125*log2e. Grid 16 x 32, XCD-chunked swizzle.
__global__ __launch_bounds__(256, 2)
void attn_kernel(const __bf16* __restrict__ Q, const __bf16* __restrict__ K,
                 const __bf16* __restrict__ Vt, const float* __restrict__ mb,
                 float* __restrict__ out) {
    __shared__ __bf16 Ks[2][64 * 64];
    __shared__ __bf16 Vs[2][64 * 64];
    __shared__ __bf16 Ps[4][64 * 64];
    const int tid  = threadIdx.x;
    const int lane = tid & 63, wid = tid >> 6;
    const int lg = lane >> 4, l15 = lane & 15;

    // XCD-aware bijective swizzle: 512 blocks, 64 consecutive per XCD ->
    // all 16 q-blocks of a (b,h) land on one XCD's L2.
    const int lin = blockIdx.x + blockIdx.y * 16;
    const int nid = (lin & 7) * 64 + (lin >> 3);
    const int qi = nid & 15, bh = nid >> 4;
    const int b = bh >> 4, h = bh & 15;
    const int qbase = qi * 256;

    // Q fragments: 4 sub-tiles of 16 q rows each (A layout: row=l15, k=lg*8+j)
    bf16x8 aq[4][2];
#pragma unroll
    for (int qm = 0; qm < 4; ++qm) {
        const __bf16* qrow = Q + (((size_t)(b * 4096 + qbase + wid * 64 + qm * 16 + l15)) << 10) + h * 64;
        aq[qm][0] = *(const bf16x8*)(qrow + lg * 8);
        aq[qm][1] = *(const bf16x8*)(qrow + 32 + lg * 8);
    }

    const f32x4 zero = {0.f, 0.f, 0.f, 0.f};
    f32x4 acc[4][4];
#pragma unroll
    for (int qm = 0; qm < 4; ++qm)
#pragma unroll
        for (int n = 0; n < 4; ++n) acc[qm][n] = zero;
    float rs[4] = {0.f, 0.f, 0.f, 0.f};

    const char* Kg = (const char*)(K + (((size_t)(b * 1024)) << 10) + h * 64);
    const char* Vg = (const char*)(Vt + (((size_t)(b * 1024 + h * 64)) << 10));
    const float* mbp = mb + b * 1024;

    char* PsB = (char*)Ps[wid];
    const int pswz = (l15 & 7) << 4;

    const char* kg[2]; const char* vg[2]; int ld[2];
#pragma unroll
    for (int p = 0; p < 2; ++p) {
        int o  = p * 4096 + tid * 16;
        int r  = o >> 7, cb = o & 127;
        int cs = cb ^ ((r & 7) << 4);
        kg[p] = Kg + (size_t)r * 2048 + cs;
        vg[p] = Vg + (size_t)r * 2048 + cs;
        ld[p] = o;
    }

#pragma unroll
    for (int p = 0; p < 2; ++p) {
        gload16(kg[p], (char*)Ks[0] + ld[p]);
        gload16(vg[p], (char*)Vs[0] + ld[p]);
    }

    int cur = 0;
    for (int kt = 0; kt < 16; ++kt) {
        __syncthreads();   // buf[cur] ready (vmcnt drained), buf[cur^1] free
        if (kt < 15) {
#pragma unroll
            for (int p = 0; p < 2; ++p) {
                gload16(kg[p] + (size_t)(kt + 1) * 131072, (char*)Ks[cur ^ 1] + ld[p]);
                gload16(vg[p] + (kt + 1) * 128,            (char*)Vs[cur ^ 1] + ld[p]);
            }
        }
        const char* KsB = (const char*)Ks[cur];
        const char* VsB = (const char*)Vs[cur];

        // K fragments (reused across 4 q sub-tiles)
        bf16x8 bk[4][2];
#pragma unroll
        for (int n = 0; n < 4; ++n)
#pragma unroll
            for (int kk = 0; kk < 2; ++kk) {
                int key = n * 16 + l15;
                bk[n][kk] = *(const bf16x8*)(KsB + key * 128 + ((kk * 64 + lg * 16) ^ ((key & 7) << 4)));
            }
        f32x4 mv[4];
#pragma unroll
        for (int n = 0; n < 4; ++n) mv[n] = *(const f32x4*)(mbp + kt * 64 + n * 16 + lg * 4);

        // per q sub-tile: S^T = K·Q^T, exp2, write P
#pragma unroll
        for (int qm = 0; qm < 4; ++qm) {
            f32x4 s[4];
#pragma unroll
            for (int n = 0; n < 4; ++n) {
                s[n] = mfma16(bk[n][0], aq[qm][0], zero);
                s[n] = mfma16(bk[n][1], aq[qm][1], s[n]);
            }
            const int prow = (qm * 16 + l15) * 128;
#pragma unroll
            for (int n = 0; n < 4; ++n) {
                float p0 = fast_exp2(s[n][0] + mv[n][0]);
                float p1 = fast_exp2(s[n][1] + mv[n][1]);
                float p2 = fast_exp2(s[n][2] + mv[n][2]);
                float p3 = fast_exp2(s[n][3] + mv[n][3]);
                rs[qm] += (p0 + p1) + (p2 + p3);
                bf16x4 o;
                o[0] = (__bf16)p0; o[1] = (__bf16)p1; o[2] = (__bf16)p2; o[3] = (__bf16)p3;
                *(bf16x4*)(PsB + prow + ((n * 32 + lg * 8) ^ pswz)) = o;
            }
        }

        // V fragments (reused across 4 q sub-tiles)
        bf16x8 bv[4][2];
#pragma unroll
        for (int n = 0; n < 4; ++n)
#pragma unroll
            for (int kk = 0; kk < 2; ++kk) {
                int d = n * 16 + l15;
                bv[n][kk] = *(const bf16x8*)(VsB + d * 128 + ((kk * 64 + lg * 16) ^ ((d & 7) << 4)));
            }
#pragma unroll
        for (int qm = 0; qm < 4; ++qm) {
            const int prow = (qm * 16 + l15) * 128;
            bf16x8 ap0 = *(const bf16x8*)(PsB + prow + ((lg * 16) ^ pswz));
            bf16x8 ap1 = *(const bf16x8*)(PsB + prow + ((64 + lg * 16) ^ pswz));
#pragma unroll
            for (int n = 0; n < 4; ++n) {
                acc[qm][n] = mfma16(ap0, bv[n][0], acc[qm][n]);
                acc[qm][n] = mfma16(ap1, bv[n][1], acc[qm][n]);
            }
        }
        cur ^= 1;
    }

    // reduce row sums over the 4 lane-groups, redistribute to epilogue layout
    float inv[4][4];
#pragma unroll
    for (int qm = 0; qm < 4; ++qm) {
        rs[qm] += __shfl_xor(rs[qm], 16);
        rs[qm] += __shfl_xor(rs[qm], 32);
#pragma unroll
        for (int r = 0; r < 4; ++r) inv[qm][r] = 1.0f / __shfl(rs[qm], lg * 4 + r);
    }

#pragma unroll
    for (int qm = 0; qm < 4; ++qm)
#pragma unroll
        for (int n = 0; n < 4; ++n)
#pragma unroll
            for (int r = 0; r < 4; ++r) {
                size_t row = (size_t)(b * 4096 + qbase + wid * 64 + qm * 16 + lg * 4 + r);
                out[(row << 10) + h * 64 + n * 16 + l15] = acc[qm][n][r] * inv[qm][r];
            }
}

extern "C" void kernel_launch(void* const* d_in, const int* in_sizes, int n_in,
                              void* d_out, int out_size, void* d_ws, size_t ws_size,
                              hipStream_t stream) {
    const float* hs    = (const float*)d_in[0];
    const int*   amask = (const int*)d_in[1];
    const float* Wq    = (const float*)d_in[2];
    const float* bq    = (const float*)d_in[3];
    const float* Wk    = (const float*)d_in[4];
    const float* bk    = (const float*)d_in[5];
    const float* Wv    = (const float*)d_in[6];
    const float* bv    = (const float*)d_in[7];
    float* out = (float*)d_out;

    char* ws = (char*)d_ws;
    size_t off = 0;
    auto alloc = [&](size_t bytes) -> char* {
        char* p = ws + off;
        off += (bytes + 255) & ~(size_t)255;
        return p;
    };
    __bf16* hsb   = (__bf16*)alloc(8388608ull * 2);  // hidden bf16 [8192][1024]
    __bf16* qb    = (__bf16*)alloc(8388608ull * 2);  // Q bf16 (pre-scaled)
    __bf16* poolb = (__bf16*)alloc(2097152ull * 2);  // pooled bf16 [2048][1024]
    __bf16* kb    = (__bf16*)alloc(2097152ull * 2);  // K bf16
    __bf16* vtb   = (__bf16*)alloc(2097152ull * 2);  // V^T bf16 [b,h,d][key]
    __bf16* wqb   = (__bf16*)alloc(1048576ull * 2);  // Wq * qscale
    __bf16* wkvb  = (__bf16*)alloc(2097152ull * 2);  // [Wk ; Wv]
    float*  mbf   = (float*)alloc(2048 * 4);

    const float qscale = 0.125f * LOG2E;   // 1/sqrt(DH) and log2(e) folded into Q

    cast_pool_kernel<<<1024, 256, 0, stream>>>(hs, hsb, poolb, 262144);
    cast_w_kernel<<<1536, 256, 0, stream>>>(Wq, Wk, Wv, wqb, wkvb, qscale, 393216);
    mask_kernel<<<8, 256, 0, stream>>>(amask, mbf, 2048);

    gemm_fused<<<768, 256, 0, stream>>>(hsb, poolb, wqb, wkvb, bq, bk, bv, qscale,
                                        qb, kb, vtb);

    attn_kernel<<<dim3(16, 32), 256, 0, stream>>>(qb, kb, vtb, mbf, out);
}